// Round 4
// baseline (140.664 us; speedup 1.0000x reference)
//
#include <hip/hip_runtime.h>

#define LDIM 1024
#define NSHIFT 10
#define ROW_V (LDIM / 4)            // 256 int4 per output row
#define BATCH_V (LDIM * ROW_V)      // 262144 int4 per batch = 2^18
#define NBATCH 32                   // fixed problem shape (B=32, L=1024)
#define TOTAL_V (NBATCH * BATCH_V)  // 8,388,608 int4 = 128 MiB logical output

#define ZBLOCKS 2048
#define ZTHREADS 256
#define ZSTRIDE (ZBLOCKS * ZTHREADS)      // 524288 threads = 8192 waves = full occupancy
#define ZITERS (TOTAL_V / ZSTRIDE)        // 16, compile-time -> fully unrolled

typedef int v4i __attribute__((ext_vector_type(4)));

// Kernel 1: branch-free pure memset of the logical 128 MiB output.
// No loads, no band logic, compile-time trip count -> 16 back-to-back
// global_store_dwordx4, perfectly coalesced (each wave: 1024 B contiguous).
// R0 vs R3 proved the branchy fill's cost was independent of bytes AND store
// count -- this removes every non-store instruction from the streaming path.
__global__ __launch_bounds__(ZTHREADS) void zero_fill(v4i* __restrict__ outv)
{
    const int f = blockIdx.x * ZTHREADS + threadIdx.x;
    const v4i z = (v4i){0, 0, 0, 0};
#pragma unroll
    for (int k = 0; k < ZITERS; ++k)
        outv[f + k * ZSTRIDE] = z;
}

// Kernel 2: band writer. One thread per output row (b,i): compute the 21 band
// bits ONCE, then store only the <=7 int4s the band intersects (~3.7 MB total),
// overwriting the zeros. Stream order guarantees zero_fill completes first.
// out[i][j] = 1 iff |i-j|<=10 and mask[k]==0 for all k in (min(i,j), max(i,j)].
__global__ __launch_bounds__(256) void band_write(
    const int* __restrict__ mask, v4i* __restrict__ outv)
{
    const int idx = blockIdx.x * 256 + threadIdx.x;  // (b<<10)|i
    const int b = idx >> 10;
    const int i = idx & (LDIM - 1);
    const int* __restrict__ mrow = mask + b * LDIM;

    unsigned int bits = 1u << NSHIFT;   // d = 0 (diagonal) always 1
    int prod = 1;
#pragma unroll
    for (int d = 1; d <= NSHIFT; ++d) { // backward: j = i-d, need mask[(j,i]] all 0
        const int k = i - d + 1;
        const int mv = (k >= 1) ? mrow[k] : 1;   // j<0 -> force 0
        prod &= (mv == 0) ? 1 : 0;
        bits |= ((unsigned int)prod) << (NSHIFT - d);
    }
    prod = 1;
#pragma unroll
    for (int d = 1; d <= NSHIFT; ++d) { // forward: j = i+d, need mask[(i,j]] all 0
        const int k = i + d;
        const int mv = (k < LDIM) ? mrow[k] : 1; // j>1023 -> force 0
        prod &= (mv == 0) ? 1 : 0;
        bits |= ((unsigned int)prod) << (NSHIFT + d);
    }

    // int4 range covering columns [max(0,i-10), min(1023,i+10)]
    const int j_lo = (i - NSHIFT > 0) ? (i - NSHIFT) : 0;
    const int j_hi = (i + NSHIFT < LDIM - 1) ? (i + NSHIFT) : (LDIM - 1);
    const int jv_lo = j_lo >> 2;
    const int jv_hi = j_hi >> 2;

    v4i* __restrict__ orow = outv + b * BATCH_V + i * ROW_V;
    for (int jv = jv_lo; jv <= jv_hi; ++jv) {
        const int base = (jv << 2) - i + NSHIFT;    // bit index for element 0
        v4i v;
        v.x = (base     >= 0 && base     <= 2 * NSHIFT) ? (int)((bits >> (base    )) & 1u) : 0;
        v.y = (base + 1 >= 0 && base + 1 <= 2 * NSHIFT) ? (int)((bits >> (base + 1)) & 1u) : 0;
        v.z = (base + 2 >= 0 && base + 2 <= 2 * NSHIFT) ? (int)((bits >> (base + 2)) & 1u) : 0;
        v.w = (base + 3 >= 0 && base + 3 <= 2 * NSHIFT) ? (int)((bits >> (base + 3)) & 1u) : 0;
        orow[jv] = v;
    }
}

extern "C" void kernel_launch(void* const* d_in, const int* in_sizes, int n_in,
                              void* d_out, int out_size, void* d_ws, size_t ws_size,
                              hipStream_t stream)
{
    (void)in_sizes; (void)n_in; (void)out_size; (void)d_ws; (void)ws_size;
    const int* mask = (const int*)d_in[0];
    v4i* outv = (v4i*)d_out;

    zero_fill<<<ZBLOCKS, ZTHREADS, 0, stream>>>(outv);
    band_write<<<(NBATCH * LDIM) / 256, 256, 0, stream>>>(mask, outv);
}

// Round 5
// 132.381 us; speedup vs baseline: 1.0626x; 1.0626x over previous
//
#include <hip/hip_runtime.h>

#define LDIM 1024
#define NSHIFT 10
#define ROW_V (LDIM / 4)            // 256 int4 per output row
#define BATCH_V (LDIM * ROW_V)      // 262144 int4 per batch = 2^18
#define NBATCH 32                   // fixed problem shape (B=32, L=1024)
#define TOTAL_V (NBATCH * BATCH_V)  // 8,388,608 int4 = 128 MiB logical output

#define BLOCKS 2048
#define THREADS 256
#define STRIDE (BLOCKS * THREADS)   // 2^19 -> 8192 waves = full occupancy
#define ITERS (TOTAL_V / STRIDE)    // 16, compile-time -> fully unrolled

typedef int v4i __attribute__((ext_vector_type(4)));

// 21 band bits for row (b,i): bit (NSHIFT + d), d in [-10,10] == out[b, i, i+d].
// out[i][j] = 1 iff |i-j|<=10 and mask[k]==0 for all k in (min(i,j), max(i,j)].
__device__ __forceinline__ unsigned int band_bits(const int* __restrict__ mrow, int i)
{
    unsigned int bits = 1u << NSHIFT;   // d = 0 (diagonal) always 1
    int prod = 1;
#pragma unroll
    for (int d = 1; d <= NSHIFT; ++d) { // backward: j = i-d
        const int k = i - d + 1;
        const int mv = (k >= 1) ? mrow[k] : 1;   // j<0 -> force 0
        prod &= (mv == 0) ? 1 : 0;
        bits |= ((unsigned int)prod) << (NSHIFT - d);
    }
    prod = 1;
#pragma unroll
    for (int d = 1; d <= NSHIFT; ++d) { // forward: j = i+d
        const int k = i + d;
        const int mv = (k < LDIM) ? mrow[k] : 1; // j>1023 -> force 0
        prod &= (mv == 0) ? 1 : 0;
        bits |= ((unsigned int)prod) << (NSHIFT + d);
    }
    return bits;
}

// Single launch, single pass over the logical 128 MiB output.
// Wave-structure invariants (STRIDE = 2^19, 64-lane waves):
//   - i = (f0>>8)&1023 and j0 are wave-uniform and iteration-invariant
//   - b_t = (f0 + t*STRIDE)>>18 = b0 + 2t with b0 = f0>>18 wave-uniform
// Band waves (~25%): lane l computes band_bits for batch b0+2*(l&15) ONCE
// (lane-parallel, one latency exposure), then __shfl broadcasts word t at
// iteration t. This is NOT round 2's per-iteration recompute.
__global__ __launch_bounds__(THREADS) void chunk_mask_onepass(
    const int* __restrict__ mask, v4i* __restrict__ outv)
{
    const int f0 = blockIdx.x * THREADS + threadIdx.x;
    const int i  = (f0 >> 8) & (LDIM - 1);      // output row within batch
    const int j0 = (f0 & (ROW_V - 1)) << 2;     // first int32 column of this int4

    const bool in_band = (j0 + 3 >= i - NSHIFT) && (j0 <= i + NSHIFT);

    if (!__any(in_band)) {
        // ~75% of waves: pure streaming store path, branch-free, fully unrolled
        const v4i z = (v4i){0, 0, 0, 0};
#pragma unroll
        for (int t = 0; t < ITERS; ++t)
            outv[f0 + t * STRIDE] = z;
    } else {
        const int lane = threadIdx.x & 63;
        const int b0   = f0 >> 18;              // wave-uniform in {0,1}
        const int my_b = b0 + 2 * (lane & 15);  // 16 batches this wave will visit
        const unsigned int my_bits = band_bits(mask + my_b * LDIM, i);

        const int base = j0 - i + NSHIFT;       // bit index for element 0 (fixed/lane)
        const bool okx = (base     >= 0) && (base     <= 2 * NSHIFT);
        const bool oky = (base + 1 >= 0) && (base + 1 <= 2 * NSHIFT);
        const bool okz = (base + 2 >= 0) && (base + 2 <= 2 * NSHIFT);
        const bool okw = (base + 3 >= 0) && (base + 3 <= 2 * NSHIFT);

#pragma unroll
        for (int t = 0; t < ITERS; ++t) {
            const unsigned int bits = (unsigned int)__shfl((int)my_bits, t, 64);
            v4i v;
            v.x = okx ? (int)((bits >> (base    )) & 1u) : 0;
            v.y = oky ? (int)((bits >> (base + 1)) & 1u) : 0;
            v.z = okz ? (int)((bits >> (base + 2)) & 1u) : 0;
            v.w = okw ? (int)((bits >> (base + 3)) & 1u) : 0;
            outv[f0 + t * STRIDE] = v;
        }
    }
}

extern "C" void kernel_launch(void* const* d_in, const int* in_sizes, int n_in,
                              void* d_out, int out_size, void* d_ws, size_t ws_size,
                              hipStream_t stream)
{
    (void)in_sizes; (void)n_in; (void)out_size; (void)d_ws; (void)ws_size;
    const int* mask = (const int*)d_in[0];
    v4i* outv = (v4i*)d_out;

    // ONE launch: fill + band in a single pass, exactly the logical 128 MiB.
    chunk_mask_onepass<<<BLOCKS, THREADS, 0, stream>>>(mask, outv);
}